// Round 4
// baseline (509.798 us; speedup 1.0000x reference)
//
#include <hip/hip_runtime.h>
#include <math.h>

// x: (8,64,384,384) fp32; params: (8,2) fp32.
#define B_  8
#define C_  64
#define H_  384
#define W_  384

// Full-width strip streaming: one block = 384-wide x RY-row strip.
// No horizontal halo (wave covers full row; halo via __shfl).
// Vertical halo only at the single strip seam: read (RY+8)/RY = 1.042x.
#define RY      192
#define NSTR    (H_ / RY)            // 2
#define NPLANE  (B_ * C_)            // 512
#define NBLK    (NPLANE * NSTR)      // 1024 = 4 blocks/CU exactly
#define RINGW   392                  // ring row stride (384 + pad)
#define NCHUNK  ((RY + 8) / 4)       // 50 input chunks of 4 rows

typedef float f2v __attribute__((ext_vector_type(2)));

template<int K>
__device__ __forceinline__ void run_strip(
    float (*ring)[RINGW],
    const float* __restrict__ xp, float* __restrict__ op,
    int sy0, float sigma, int tid)
{
    constexpr int  PAD  = K / 2;
    constexpr bool EVEN = ((K & 1) == 0);
    const int wv = tid >> 6;        // wave 0..3: handles raw row (chunk*4 + wv)
    const int ln = tid & 63;
    const int x0 = 6 * ln;          // this lane's 6 columns (64*6 = 384)

    // normalized 1D Gaussian weights, in registers
    float g[K];
    {
        const float inv2s2 = 1.0f / (2.0f * sigma * sigma);
        float S = 0.0f;
        #pragma unroll
        for (int i = 0; i < K; ++i) {
            float d = (float)(i - PAD);
            g[i] = expf(-d * d * inv2s2);
            S += g[i];
        }
        const float invS = 1.0f / S;
        #pragma unroll
        for (int i = 0; i < K; ++i) g[i] *= invS;
    }

    // load one raw input row (6 floats) for chunk j into registers
    auto loadrow = [&](float (&d)[6], int j) {
        const int r = sy0 - 4 + 4 * j + wv;
        if (j < NCHUNK && r >= 0 && r < H_) {
            const float* rp = xp + (size_t)r * W_ + x0;
            f2v a = *reinterpret_cast<const f2v*>(rp);
            f2v b = *reinterpret_cast<const f2v*>(rp + 2);
            f2v c = *reinterpret_cast<const f2v*>(rp + 4);
            d[0] = a.x; d[1] = a.y; d[2] = b.x;
            d[3] = b.y; d[4] = c.x; d[5] = c.y;
        } else {
            #pragma unroll
            for (int i = 0; i < 6; ++i) d[i] = 0.f;
        }
    };

    // One pipeline step: prefetch chunk j+1, H-filter chunk j into the ring,
    // barrier, V-emit output chunk j-2.  Ring slot disjointness (16 slots,
    // V reads (4j-8..4j+3)&15, next H writes (4j+4..4j+7)&15) => 1 barrier/step.
    auto step = [&](int j, float (&cur)[6], float (&nxt)[6]) {
        loadrow(nxt, j + 1);   // in flight across barrier + V-phase

        // ---- horizontal pass (this wave's raw row), halo via shuffles ----
        // window w[0..13] = cols x0-4 .. x0+9
        float w[14];
        #pragma unroll
        for (int i = 0; i < 6; ++i) w[4 + i] = cur[i];
        #pragma unroll
        for (int i = 0; i < 4; ++i) {
            float t = __shfl_up(cur[2 + i], 1, 64);
            w[i] = (ln == 0) ? 0.f : t;          // cols <0 zero-pad
        }
        #pragma unroll
        for (int i = 0; i < 4; ++i) {
            float t = __shfl_down(cur[i], 1, 64);
            w[10 + i] = (ln == 63) ? 0.f : t;    // cols >=384 zero-pad
        }

        float hv[6];
        #pragma unroll
        for (int cc = 0; cc < 6; ++cc) {
            float a0 = 0.f;
            #pragma unroll
            for (int t = 0; t < K; ++t) a0 += g[t] * w[cc + 4 - PAD + t];
            float val = a0;
            if (EVEN) {
                float a1 = 0.f;
                #pragma unroll
                for (int t = 0; t < K; ++t) a1 += g[t] * w[cc + 5 - PAD + t];
                const float fw = ((float)(x0 + cc) + 0.5f) * (1.0f / (float)W_);
                val = a0 + fw * (a1 - a0);
            }
            hv[cc] = val;
        }
        const int slot = (4 * j + wv) & 15;
        f2v p0 = { hv[0], hv[1] }, p1 = { hv[2], hv[3] }, p2 = { hv[4], hv[5] };
        *reinterpret_cast<f2v*>(&ring[slot][x0])     = p0;
        *reinterpret_cast<f2v*>(&ring[slot][x0 + 2]) = p1;
        *reinterpret_cast<f2v*>(&ring[slot][x0 + 4]) = p2;

        __syncthreads();

        // ---- vertical pass: output chunk m = j-2 (4 rows), 192 threads x 2 cols
        if (j >= 2 && tid < 192) {
            const int m  = j - 2;
            const int xx = 2 * tid;              // 0..382
            f2v U[12];
            #pragma unroll
            for (int i = 0; i < 12; ++i)         // rows sy0+4m-4 .. sy0+4m+7
                U[i] = *reinterpret_cast<const f2v*>(&ring[(4 * m + i) & 15][xx]);
            #pragma unroll
            for (int jj = 0; jj < 4; ++jj) {
                f2v a0 = { 0.f, 0.f };
                #pragma unroll
                for (int t = 0; t < K; ++t) a0 += g[t] * U[jj + 4 - PAD + t];
                f2v val = a0;
                const int y = sy0 + 4 * m + jj;
                if (EVEN) {
                    f2v a1 = { 0.f, 0.f };
                    #pragma unroll
                    for (int t = 0; t < K; ++t) a1 += g[t] * U[jj + 5 - PAD + t];
                    const float fh = ((float)y + 0.5f) * (1.0f / (float)H_);
                    val = a0 + fh * (a1 - a0);
                }
                __builtin_nontemporal_store(val,
                    reinterpret_cast<f2v*>(&op[(size_t)y * W_ + xx]));
            }
        }
    };

    // register double-buffer: named bufs, statically alternated (no scratch)
    float bufA[6], bufB[6];
    loadrow(bufA, 0);
    for (int jj = 0; jj < NCHUNK / 2; ++jj) {
        step(2 * jj,     bufA, bufB);
        step(2 * jj + 1, bufB, bufA);
    }
}

__global__ __launch_bounds__(256) void gauss_blur_kernel(
    const float* __restrict__ x, const float* __restrict__ params,
    float* __restrict__ out)
{
    // Bijective XCD swizzle; strips of the same plane adjacent in time/XCD,
    // so the single seam re-read (8 rows) hits L2.
    const int bid   = blockIdx.x;                       // 0..1023
    const int gidx  = (bid & 7) * (NBLK / 8) + (bid >> 3);
    const int strip = gidx & (NSTR - 1);
    const int p     = gidx / NSTR;                      // 0..511
    const int c     = p & (C_ - 1);
    const int b     = p >> 6;
    const int sy0   = strip * RY;

    // per-batch params
    const float p0 = params[2 * b + 0];
    const float p1 = params[2 * b + 1];
    const float k_int = truncf(p0);                     // torch .long() truncation
    const float s0 = 1.0f / (1.0f + expf(-k_int));
    int k = (int)floorf(5.0f + 5.0f * s0);              // {5..9}
    if (k < 5) k = 5;
    if (k > 9) k = 9;
    const float sigma = 0.5f + 4.5f * (1.0f / (1.0f + expf(-p1)));

    __shared__ float ring[16][RINGW];                   // 25,088 B -> 4+ blocks/CU

    const size_t plane = (size_t)(b * C_ + c) * (size_t)(H_ * W_);
    const float* xp = x + plane;
    float*       op = out + plane;

    switch (k) {   // block-uniform (k depends only on b)
        case 5:  run_strip<5>(ring, xp, op, sy0, sigma, threadIdx.x); break;
        case 6:  run_strip<6>(ring, xp, op, sy0, sigma, threadIdx.x); break;
        case 7:  run_strip<7>(ring, xp, op, sy0, sigma, threadIdx.x); break;
        case 8:  run_strip<8>(ring, xp, op, sy0, sigma, threadIdx.x); break;
        default: run_strip<9>(ring, xp, op, sy0, sigma, threadIdx.x); break;
    }
}

extern "C" void kernel_launch(void* const* d_in, const int* in_sizes, int n_in,
                              void* d_out, int out_size, void* d_ws, size_t ws_size,
                              hipStream_t stream) {
    const float* x      = (const float*)d_in[0];
    const float* params = (const float*)d_in[1];
    float* out          = (float*)d_out;

    dim3 grid(NBLK, 1, 1);    // 1024 blocks = 4 resident per CU
    dim3 block(256, 1, 1);
    gauss_blur_kernel<<<grid, block, 0, stream>>>(x, params, out);
}